// Round 4
// baseline (135.575 us; speedup 1.0000x reference)
//
#include <hip/hip_runtime.h>
#include <hip/hip_fp16.h>

// Batched quantum-circuit sim. ONE kernel, 2x grid: first half of blocks run
// the three 4-qubit circuits (A,B,C), second half the 7-qubit circuit (D) --
// doubles resident waves (grid was occupancy-limiting at 2 waves/SIMD).
// State: __half2 (re,im) per amplitude, gates = v_pk_fma_f16.
// Depth loop fully unrolled so all CNOT/parity permutations are register
// renames (rolled version materialized ~770 v_movs).

#define DEVINL __device__ __forceinline__

typedef _Float16 hv2 __attribute__((ext_vector_type(2)));

struct C2 { __half2 rr, mp; };  // complex const (r,i): rr=(r,r), mp=(-i,+i)

DEVINL C2 mkc(float re, float im) {
  C2 c; c.rr = __floats2half2_rn(re, re); c.mp = __floats2half2_rn(-im, im); return c;
}
DEVINL __half2 mkamp(float re, float im) { return __floats2half2_rn(re, im); }
DEVINL __half2 swap2(__half2 v) { return __lowhigh2highlow(v); }
// (const u) * (amp v):  (r*vr - i*vi, r*vi + i*vr)
DEVINL __half2 cmulc(C2 u, __half2 v) { return __hfma2(u.rr, v, __hmul2(u.mp, swap2(v))); }

DEVINL float ampsq(__half2 v, float acc) {
#if __has_builtin(__builtin_amdgcn_fdot2)
  return __builtin_amdgcn_fdot2(__builtin_bit_cast(hv2, v), __builtin_bit_cast(hv2, v), acc, false);
#else
  float2 f = __half22float2(v);
  return fmaf(f.x, f.x, fmaf(f.y, f.y, acc));
#endif
}

constexpr int parc(int x) { x ^= x >> 4; x ^= x >> 2; x ^= x >> 1; return x & 1; }

struct c32 { float x, y; };
DEVINL c32 cmulf(c32 a, c32 b) { return { a.x*b.x - a.y*b.y, a.x*b.y + a.y*b.x }; }

// ---------------- gates (qubit W of N; mask = 1<<(N-1-W)) -------------------

template<int N, int W>
DEVINL void g_ry(__half2* a, __half2 c2, __half2 s2, __half2 ns2) {
  constexpr int M = 1 << (N - 1 - W);
#pragma unroll
  for (int i = 0; i < (1 << N); ++i) if (!(i & M)) {
    const int j = i | M;
    __half2 v0 = a[i], v1 = a[j];
    a[i] = __hfma2(c2, v0, __hmul2(ns2, v1));
    a[j] = __hfma2(c2, v1, __hmul2(s2, v0));
  }
}

template<int N, int W>
DEVINL void g_u2(__half2* a, C2 u00, C2 u01, C2 u10, C2 u11) {
  constexpr int M = 1 << (N - 1 - W);
#pragma unroll
  for (int i = 0; i < (1 << N); ++i) if (!(i & M)) {
    const int j = i | M;
    __half2 v0 = a[i], v1 = a[j], v0s = swap2(v0), v1s = swap2(v1);
    a[i] = __hfma2(u00.rr, v0, __hfma2(u00.mp, v0s, __hfma2(u01.rr, v1, __hmul2(u01.mp, v1s))));
    a[j] = __hfma2(u10.rr, v0, __hfma2(u10.mp, v0s, __hfma2(u11.rr, v1, __hmul2(u11.mp, v1s))));
  }
}

template<int N, int C, int T>
DEVINL void g_cnot(__half2* a) {
  constexpr int CM = 1 << (N - 1 - C), TM = 1 << (N - 1 - T);
#pragma unroll
  for (int i = 0; i < (1 << N); ++i) if ((i & CM) && !(i & TM)) {
    const int j = i | TM;
    __half2 t = a[i]; a[i] = a[j]; a[j] = t;
  }
}

template<int N, int K>
DEVINL void chain_cnot(__half2* a) {
  if constexpr (K < N - 1) { g_cnot<N, K, K + 1>(a); chain_cnot<N, K + 1>(a); }
}

// ---------------- per-qubit coefficients (f32) ------------------------------
// forward: u = Rz(phi)Ry(pt)Rx(eta)|0>;  reverse merged: U = Rx(phi)Ry(pt)Rz(eta)

DEVINL void mk_u01(float ce, float se, float cp, float sp, float cf, float sf,
                   c32& u0, c32& u1) {
  u0 = cmulf({cf, -sf}, {cp * ce, sp * se});
  u1 = cmulf({cf,  sf}, {sp * ce, -cp * se});
}

DEVINL void mk_U(float ce, float se, float cp, float sp, float cf, float sf,
                 C2& U00, C2& U01, C2& U10, C2& U11) {
  c32 z = {ce, -se}, zb = {ce, se};
  c32 A = cmulf({cf * cp, -sf * sp}, z);
  c32 T = cmulf({cf * sp,  sf * cp}, zb);
  c32 Cc = cmulf({cf * sp, -sf * cp}, z);
  c32 D = cmulf({cf * cp,  sf * sp}, zb);
  U00 = mkc(A.x, A.y); U01 = mkc(-T.x, -T.y); U10 = mkc(Cc.x, Cc.y); U11 = mkc(D.x, D.y);
}

// product state build by doubling (a[0] must be (1,0) on entry)
template<int N, int M>
DEVINL void build_step(__half2* a, const float* ce, const float* se, const float* cp,
                       const float* sp, const float* cf, const float* sf) {
  if constexpr (M < N) {
    c32 u0, u1; mk_u01(ce[M], se[M], cp[M], sp[M], cf[M], sf[M], u0, u1);
    C2 c0 = mkc(u0.x, u0.y), c1 = mkc(u1.x, u1.y);
#pragma unroll
    for (int j = (1 << M) - 1; j >= 0; --j) {
      __half2 s = a[j];
      a[2 * j]     = cmulc(c0, s);
      a[2 * j + 1] = cmulc(c1, s);
    }
    build_step<N, M + 1>(a, ce, se, cp, sp, cf, sf);
  }
}

template<int N, int K>
DEVINL void u_sweep(__half2* a, const float* ce, const float* se, const float* cp,
                    const float* sp, const float* cf, const float* sf) {
  if constexpr (K < N) {
    C2 U00, U01, U10, U11;
    mk_U(ce[K], se[K], cp[K], sp[K], cf[K], sf[K], U00, U01, U10, U11);
    g_u2<N, K>(a, U00, U01, U10, U11);
    u_sweep<N, K + 1>(a, ce, se, cp, sp, cf, sf);
  }
}

template<int N, int K>
DEVINL void ry_sweep(__half2* a, const __half2* c2, const __half2* s2, const __half2* ns2) {
  if constexpr (K < N) {
    g_ry<N, K>(a, c2[K], s2[K], ns2[K]);
    ry_sweep<N, K + 1>(a, c2, s2, ns2);
  }
}

// ---------------- 4-qubit block I: latent=(0,1) trash=(2,3) depth=1 ---------

template<int I>
DEVINL void sim4h(const float* r, const float* __restrict__ w, float* z) {
  constexpr int PT[3][4]  = {{5, 4, 35, 34}, {3, 33, 31, 2}, {28, 32, 15, 16}};
  constexpr int ETA[3][4] = {{9, 8, 45, 44}, {7, 43, 41, 6}, {38, 42, 19, 20}};
  constexpr int PHI[3][4] = {{13, 12, 55, 54}, {11, 53, 51, 10}, {48, 52, 23, 24}};
  float ce[4], se[4], cp[4], sp[4], cf[4], sf[4];
#pragma unroll
  for (int k = 0; k < 4; ++k) {
    __sincosf(0.5f * r[ETA[I][k]], &se[k], &ce[k]);
    __sincosf(0.5f * r[PT[I][k]],  &sp[k], &cp[k]);
    __sincosf(0.5f * r[PHI[I][k]], &sf[k], &cf[k]);
  }
  __half2 a[16];
  a[0] = mkamp(1.f, 0.f);
  build_step<4, 0>(a, ce, se, cp, sp, cf, sf);
  chain_cnot<4, 0>(a);
  u_sweep<4, 0>(a, ce, se, cp, sp, cf, sf);

  // t->l CNOT block == flip q0,q1 (mask 12) iff parity(b2,b3) (i&3)
#pragma unroll
  for (int i = 0; i < 16; ++i)
    if (parc(i & 3) && !(i & 8)) { __half2 t = a[i]; a[i] = a[i ^ 12]; a[i ^ 12] = t; }

  __half2 c2[4], s2[4], ns2[4];
#pragma unroll
  for (int k = 0; k < 4; ++k) {
    float sv, cv; __sincosf(0.5f * w[k], &sv, &cv);
    c2[k] = __floats2half2_rn(cv, cv);
    s2[k] = __floats2half2_rn(sv, sv);
    ns2[k] = __floats2half2_rn(-sv, -sv);
  }
  ry_sweep<4, 0>(a, c2, s2, ns2);

  // l->t CNOT block == flip q2,q3 (mask 3) iff parity(b0,b1) (i&12)
#pragma unroll
  for (int i = 0; i < 16; ++i)
    if (parc(i & 12) && !(i & 2)) { __half2 t = a[i]; a[i] = a[i ^ 3]; a[i ^ 3] = t; }

  float cls[4];
#pragma unroll
  for (int c = 0; c < 4; ++c) cls[c] = 0.f;
#pragma unroll
  for (int i = 0; i < 16; ++i) cls[i & 3] = ampsq(a[i], cls[i & 3]);
  float z0 = 0.f, z1 = 0.f;
#pragma unroll
  for (int c = 0; c < 4; ++c) {
    z0 += (c & 2) ? -cls[c] : cls[c];
    z1 += (c & 1) ? -cls[c] : cls[c];
  }
  z[0] = z0; z[1] = z1;
}

// ---------------- 7-qubit block: latent=(0..3) trash=(4,5,6) depth=4 --------

DEVINL void sim7h(const float* r, const float* __restrict__ wD, float* z) {
  constexpr int PT[7]  = {0, 14, 30, 26, 29, 27, 17};
  constexpr int ETA[7] = {-1, 18, 40, 36, 39, 37, 21};  // -1 -> zeros (None)
  constexpr int PHI[7] = {1, 22, 50, 46, 49, 47, 25};
  float ce[7], se[7], cp[7], sp[7], cf[7], sf[7];
#pragma unroll
  for (int k = 0; k < 7; ++k) {
    float e = (ETA[k] < 0) ? 0.f : r[ETA[k]];
    __sincosf(0.5f * e, &se[k], &ce[k]);
    __sincosf(0.5f * r[PT[k]],  &sp[k], &cp[k]);
    __sincosf(0.5f * r[PHI[k]], &sf[k], &cf[k]);
  }
  __half2 a[128];
  a[0] = mkamp(1.f, 0.f);
  build_step<7, 0>(a, ce, se, cp, sp, cf, sf);
  chain_cnot<7, 0>(a);
  u_sweep<7, 0>(a, ce, se, cp, sp, cf, sf);

  // depth loop FULLY UNROLLED: parity permutations become register renames
#pragma unroll
  for (int d = 0; d < 4; ++d) {
    // t->l block == flip q0..q3 (mask 0x78) iff parity(b4,b5,b6) (i&7)
#pragma unroll
    for (int i = 0; i < 128; ++i)
      if (parc(i & 7) && !(i & 64)) { __half2 t = a[i]; a[i] = a[i ^ 0x78]; a[i ^ 0x78] = t; }

    __half2 c2[7], s2[7], ns2[7];
#pragma unroll
    for (int k = 0; k < 7; ++k) {
      float sv, cv; __sincosf(0.5f * wD[d * 7 + k], &sv, &cv);
      c2[k] = __floats2half2_rn(cv, cv);
      s2[k] = __floats2half2_rn(sv, sv);
      ns2[k] = __floats2half2_rn(-sv, -sv);
    }
    ry_sweep<7, 0>(a, c2, s2, ns2);

    // l->t block == flip q4..q6 (mask 7) iff parity(b0..b3) (i&0x78)
#pragma unroll
    for (int i = 0; i < 128; ++i)
      if (parc(i & 0x78) && !(i & 4)) { __half2 t = a[i]; a[i] = a[i ^ 7]; a[i ^ 7] = t; }
  }

  float cls[8];
#pragma unroll
  for (int c = 0; c < 8; ++c) cls[c] = 0.f;
#pragma unroll
  for (int i = 0; i < 128; ++i) cls[i & 7] = ampsq(a[i], cls[i & 7]);
  float z4 = 0.f, z5 = 0.f, z6 = 0.f;
#pragma unroll
  for (int c = 0; c < 8; ++c) {
    z4 += (c & 4) ? -cls[c] : cls[c];
    z5 += (c & 2) ? -cls[c] : cls[c];
    z6 += (c & 1) ? -cls[c] : cls[c];
  }
  z[0] = z4; z[1] = z5; z[2] = z6;
}

// ---------------- kernel -----------------------------------------------------

__global__ void __launch_bounds__(256, 2)
k_all(const float* __restrict__ x,
      const float* __restrict__ wA, const float* __restrict__ wB,
      const float* __restrict__ wC, const float* __restrict__ wD,
      float* __restrict__ out, int B) {
  const int nb = (int)(gridDim.x >> 1);   // blocks per half
  const bool d_half = (int)blockIdx.x >= nb;
  const int blk = d_half ? ((int)blockIdx.x - nb) : (int)blockIdx.x;
  const int b = blk * 256 + threadIdx.x;
  if (b >= B) return;

  // whole row, coalesced 16B loads (row stride 224B is 16B-aligned)
  float r[56];
  const float4* row4 = (const float4*)(x + (size_t)b * 56);
#pragma unroll
  for (int i = 0; i < 14; ++i) {
    float4 v = row4[i];
    r[4 * i] = v.x; r[4 * i + 1] = v.y; r[4 * i + 2] = v.z; r[4 * i + 3] = v.w;
  }

  float* op = out + (size_t)b * 9;
  if (!d_half) {
    float o[6];
    sim4h<0>(r, wA, &o[0]);
    sim4h<1>(r, wB, &o[2]);
    sim4h<2>(r, wC, &o[4]);
#pragma unroll
    for (int i = 0; i < 6; ++i) op[i] = o[i];
  } else {
    float o[3];
    sim7h(r, wD, o);
    op[6] = o[0]; op[7] = o[1]; op[8] = o[2];
  }
}

// ---------------- launch ----------------------------------------------------

extern "C" void kernel_launch(void* const* d_in, const int* in_sizes, int n_in,
                              void* d_out, int out_size, void* d_ws, size_t ws_size,
                              hipStream_t stream) {
  const float* x  = (const float*)d_in[0];
  const float* wA = (const float*)d_in[1];
  const float* wB = (const float*)d_in[2];
  const float* wC = (const float*)d_in[3];
  const float* wD = (const float*)d_in[4];
  float* out = (float*)d_out;
  const int B = in_sizes[0] / 56;
  const int threads = 256;
  const int nb = (B + threads - 1) / threads;
  k_all<<<2 * nb, threads, 0, stream>>>(x, wA, wB, wC, wD, out, B);
}